// Round 5
// baseline (624.842 us; speedup 1.0000x reference)
//
#include <hip/hip_runtime.h>
#include <math.h>

// BeliveMapsNMS: 7x7 same-padded max-pool NMS on [32,4,512,512] f32.
// Outputs (concat flat): mask(0/1 f32), scores_abs, scores_rel.
// R5: barrier-free, LDS-free streaming NMS. NT stores restored (R4 proved
//     cached stores cost +28 us). Each WAVE owns a full 512-col x 8-row band:
//     8 cols/lane, 28 independent float4 loads in flight, vertical van Herk
//     in registers, horizontal halo via lane shuffles, centers in registers,
//     NT stores issued continuously (no phase burst, no __syncthreads).

#define H 512
#define W 512
#define PLANE_ELEMS (H * W)   // 262144
#define NEG_INF (-INFINITY)
#define VCHUNKS 16            // vmax chunks per plane

typedef float v4f __attribute__((ext_vector_type(4)));  // native vec for nontemporal

__device__ __forceinline__ float4 vmax4(float4 a, float4 b) {
    return make_float4(fmaxf(a.x, b.x), fmaxf(a.y, b.y), fmaxf(a.z, b.z), fmaxf(a.w, b.w));
}

__device__ __forceinline__ void nt_store4(float* p, float a, float b, float c, float d) {
    v4f v = {a, b, c, d};
    __builtin_nontemporal_store(v, (v4f*)p);
}

// ---------------- Pass 1: per-plane max (partials, no atomics) ----------------
__global__ __launch_bounds__(256) void vmax_kernel(const float* __restrict__ in,
                                                   float* __restrict__ partials) {
    const int chunk = blockIdx.x;  // 16 chunks of 16384 floats
    const int plane = blockIdx.y;  // 128 planes
    const float4* p = (const float4*)(in + (size_t)plane * PLANE_ELEMS) + chunk * 4096;
    float4 v[16];
    #pragma unroll
    for (int j = 0; j < 16; ++j) v[j] = p[threadIdx.x + (j << 8)];
    float4 t[8];
    #pragma unroll
    for (int j = 0; j < 8; ++j) t[j] = vmax4(v[j], v[j + 8]);
    #pragma unroll
    for (int j = 0; j < 4; ++j) t[j] = vmax4(t[j], t[j + 4]);
    float4 q = vmax4(vmax4(t[0], t[1]), vmax4(t[2], t[3]));
    float m = fmaxf(fmaxf(q.x, q.y), fmaxf(q.z, q.w));
    #pragma unroll
    for (int o = 32; o > 0; o >>= 1) m = fmaxf(m, __shfl_down(m, o, 64));
    __shared__ float s[4];
    if ((threadIdx.x & 63) == 0) s[threadIdx.x >> 6] = m;
    __syncthreads();
    if (threadIdx.x == 0) {
        partials[(plane << 4) + chunk] = fmaxf(fmaxf(s[0], s[1]), fmaxf(s[2], s[3]));
    }
}

// ---------------- Pass 2: NMS (barrier-free) ----------------
__global__ __launch_bounds__(256, 2) void nms_kernel(const float* __restrict__ in,
                                                     const float* __restrict__ partials,
                                                     float* __restrict__ out, int N) {
    // XCD-chunked swizzle: 2048 workgroups = 8 XCDs x 256 (bijective, 2048%8==0).
    const int hwid = blockIdx.x + (blockIdx.y << 4);   // gridDim.x = 16
    const int wg = ((hwid & 7) << 8) + (hwid >> 3);
    const int plane = wg >> 4;                          // 16 blocks per plane
    const int wid = threadIdx.x >> 6;
    const int lane = threadIdx.x & 63;
    const int band = ((wg & 15) << 2) + wid;            // 0..63, 8 rows each
    const int gy0 = band << 3;                          // first output row
    const int c = lane << 3;                            // 8 cols per lane

    const float* pin = in + (size_t)plane * PLANE_ELEMS;

    // 28 independent float4 loads, all in flight; OOB rows via clamp+select.
    float4 rA[14], rB[14];
    #pragma unroll
    for (int k = 0; k < 14; ++k) {
        const int gy = gy0 + k - 3;
        const int gyc = gy < 0 ? 0 : (gy > H - 1 ? H - 1 : gy);
        const float* p = pin + (size_t)gyc * W + c;
        float4 a = *(const float4*)p;
        float4 b = *(const float4*)(p + 4);
        if (gy != gyc) {   // wave-uniform
            a = make_float4(NEG_INF, NEG_INF, NEG_INF, NEG_INF);
            b = make_float4(NEG_INF, NEG_INF, NEG_INF, NEG_INF);
        }
        rA[k] = a; rB[k] = b;
    }

    // Plane max from the 16 partials (one cacheline, broadcast).
    const float4 pm0 = *(const float4*)&partials[(plane << 4) + 0];
    const float4 pm1 = *(const float4*)&partials[(plane << 4) + 4];
    const float4 pm2 = *(const float4*)&partials[(plane << 4) + 8];
    const float4 pm3 = *(const float4*)&partials[(plane << 4) + 12];
    const float4 q = vmax4(vmax4(pm0, pm1), vmax4(pm2, pm3));
    const float vmax = fmaxf(fmaxf(q.x, q.y), fmaxf(q.z, q.w));
    const float rel_thr = 0.05f * vmax;
    const float inv_vmax = 1.0f / vmax;

    // Vertical suffix maxes over rows 0..6: AA[j] = max(r[j..6]).
    float4 AA[7], AB[7];
    AA[6] = rA[6]; AB[6] = rB[6];
    #pragma unroll
    for (int j = 5; j >= 0; --j) {
        AA[j] = vmax4(rA[j], AA[j + 1]);
        AB[j] = vmax4(rB[j], AB[j + 1]);
    }

    float* __restrict__ omask = out;
    float* __restrict__ oabs = out + (size_t)N;
    float* __restrict__ orel = out + 2 * (size_t)N;

    float4 BA, BB;
    #pragma unroll
    for (int i = 0; i < 8; ++i) {
        // vertical 7-max for output row i: max(r[i..i+6])
        float4 mA, mB;
        if (i == 0) {
            mA = AA[0]; mB = AB[0];
        } else {
            if (i == 1) { BA = rA[7]; BB = rB[7]; }
            else        { BA = vmax4(BA, rA[i + 6]); BB = vmax4(BB, rB[i + 6]); }
            if (i == 7) { mA = BA; mB = BB; }
            else        { mA = vmax4(AA[i], BA); mB = vmax4(AB[i], BB); }
        }

        // horizontal halos from neighbor lanes (lane owns cols c..c+7)
        float l0 = __shfl_up(mB.y, 1, 64), l1 = __shfl_up(mB.z, 1, 64), l2 = __shfl_up(mB.w, 1, 64);
        float r0 = __shfl_down(mA.x, 1, 64), r1 = __shfl_down(mA.y, 1, 64), r2 = __shfl_down(mA.z, 1, 64);
        if (lane == 0)  { l0 = NEG_INF; l1 = NEG_INF; l2 = NEG_INF; }
        if (lane == 63) { r0 = NEG_INF; r1 = NEG_INF; r2 = NEG_INF; }
        const float a[14] = {l0, l1, l2, mA.x, mA.y, mA.z, mA.w,
                             mB.x, mB.y, mB.z, mB.w, r0, r1, r2};
        // horizontal van Herk: hm[t] = max(a[t..t+6]), t=0..7
        float A[7];
        A[6] = a[6];
        #pragma unroll
        for (int j = 5; j >= 0; --j) A[j] = fmaxf(a[j], A[j + 1]);
        float hm[8];
        hm[0] = A[0];
        float Bh = a[7];
        hm[1] = fmaxf(A[1], Bh);
        #pragma unroll
        for (int j = 2; j <= 6; ++j) { Bh = fmaxf(Bh, a[6 + j]); hm[j] = fmaxf(A[j], Bh); }
        Bh = fmaxf(Bh, a[13]);
        hm[7] = Bh;

        // centers already in registers
        const float4 cA = rA[i + 3], cB = rB[i + 3];
        const bool p0 = (hm[0] == cA.x) & (cA.x > 0.2f) & (cA.x > rel_thr);
        const bool p1 = (hm[1] == cA.y) & (cA.y > 0.2f) & (cA.y > rel_thr);
        const bool p2 = (hm[2] == cA.z) & (cA.z > 0.2f) & (cA.z > rel_thr);
        const bool p3 = (hm[3] == cA.w) & (cA.w > 0.2f) & (cA.w > rel_thr);
        const bool p4 = (hm[4] == cB.x) & (cB.x > 0.2f) & (cB.x > rel_thr);
        const bool p5 = (hm[5] == cB.y) & (cB.y > 0.2f) & (cB.y > rel_thr);
        const bool p6 = (hm[6] == cB.z) & (cB.z > 0.2f) & (cB.z > rel_thr);
        const bool p7 = (hm[7] == cB.w) & (cB.w > 0.2f) & (cB.w > rel_thr);
        const float s0 = p0 ? cA.x : 0.0f, s1 = p1 ? cA.y : 0.0f;
        const float s2 = p2 ? cA.z : 0.0f, s3 = p3 ? cA.w : 0.0f;
        const float s4 = p4 ? cB.x : 0.0f, s5 = p5 ? cB.y : 0.0f;
        const float s6 = p6 ? cB.z : 0.0f, s7 = p7 ? cB.w : 0.0f;

        const int gy = gy0 + i;
        const size_t o = (size_t)plane * PLANE_ELEMS + (size_t)gy * W + c;
        nt_store4(omask + o,     p0 ? 1.0f : 0.0f, p1 ? 1.0f : 0.0f,
                                 p2 ? 1.0f : 0.0f, p3 ? 1.0f : 0.0f);
        nt_store4(omask + o + 4, p4 ? 1.0f : 0.0f, p5 ? 1.0f : 0.0f,
                                 p6 ? 1.0f : 0.0f, p7 ? 1.0f : 0.0f);
        nt_store4(oabs + o,     s0, s1, s2, s3);
        nt_store4(oabs + o + 4, s4, s5, s6, s7);
        nt_store4(orel + o,     s0 * inv_vmax, s1 * inv_vmax, s2 * inv_vmax, s3 * inv_vmax);
        nt_store4(orel + o + 4, s4 * inv_vmax, s5 * inv_vmax, s6 * inv_vmax, s7 * inv_vmax);
    }
}

extern "C" void kernel_launch(void* const* d_in, const int* in_sizes, int n_in,
                              void* d_out, int out_size, void* d_ws, size_t ws_size,
                              hipStream_t stream) {
    const float* in = (const float*)d_in[0];
    float* out = (float*)d_out;
    const int N = in_sizes[0];           // 33554432
    const int planes = N / PLANE_ELEMS;  // 128

    float* partials = (float*)d_ws;      // 128*16 floats = 8 KB

    vmax_kernel<<<dim3(VCHUNKS, planes), 256, 0, stream>>>(in, partials);
    nms_kernel<<<dim3(16, planes), 256, 0, stream>>>(in, partials, out, N);
}

// Round 6
// 480.027 us; speedup vs baseline: 1.3017x; 1.3017x over previous
//
#include <hip/hip_runtime.h>
#include <math.h>

// BeliveMapsNMS: 7x7 same-padded max-pool NMS on [32,4,512,512] f32.
// Outputs (concat flat): mask(0/1 f32), scores_abs, scores_rel.
// R6: restore R2 structure (best measured, 477 us) with two edits:
//  - Phase-B stores reordered STREAM-MAJOR (4 mask, then 4 abs, then 4 rel
//    per thread) -> each wave's NT traffic is locally single-stream, matching
//    the fill kernel's 6.35 TB/s pattern. R5 counters proved store-instruction
//    contiguity/locality is the live mechanism (WRITE_SIZE 636 vs 402 MB).
//  - vmax: 32 chunks/plane (4096 blocks) for 2x TLP in pass 1.
// Everything else identical to R2 (TH=8, shuffle hmax, LDS rowmax, vertical
// van Herk, XCD-chunked swizzle, NT stores, launch_bounds(256,4)).

#define H 512
#define W 512
#define PLANE_ELEMS (H * W)   // 262144
#define TH 8                  // output rows per block
#define LROWS (TH + 6)        // 14 loaded rows
#define NEG_INF (-INFINITY)
#define VCHUNKS 32            // vmax chunks per plane

typedef float v4f __attribute__((ext_vector_type(4)));  // native vec for nontemporal

__device__ __forceinline__ float4 vmax4(float4 a, float4 b) {
    return make_float4(fmaxf(a.x, b.x), fmaxf(a.y, b.y), fmaxf(a.z, b.z), fmaxf(a.w, b.w));
}

__device__ __forceinline__ void nt_store4(float* p, float a, float b, float c, float d) {
    v4f v = {a, b, c, d};
    __builtin_nontemporal_store(v, (v4f*)p);
}

// ---------------- Pass 1: per-plane max (partials, no atomics) ----------------
__global__ __launch_bounds__(256) void vmax_kernel(const float* __restrict__ in,
                                                   float* __restrict__ partials) {
    const int chunk = blockIdx.x;  // 32 chunks of 8192 floats
    const int plane = blockIdx.y;  // 128 planes
    const float4* p = (const float4*)(in + (size_t)plane * PLANE_ELEMS) + chunk * 2048;
    float4 v[8];
    #pragma unroll
    for (int j = 0; j < 8; ++j) v[j] = p[threadIdx.x + (j << 8)];
    float4 t[4];
    #pragma unroll
    for (int j = 0; j < 4; ++j) t[j] = vmax4(v[j], v[j + 4]);
    float4 q = vmax4(vmax4(t[0], t[1]), vmax4(t[2], t[3]));
    float m = fmaxf(fmaxf(q.x, q.y), fmaxf(q.z, q.w));
    #pragma unroll
    for (int o = 32; o > 0; o >>= 1) m = fmaxf(m, __shfl_down(m, o, 64));
    __shared__ float s[4];
    if ((threadIdx.x & 63) == 0) s[threadIdx.x >> 6] = m;
    __syncthreads();
    if (threadIdx.x == 0) {
        // every slot written each launch -> no init needed
        partials[(plane << 5) + chunk] = fmaxf(fmaxf(s[0], s[1]), fmaxf(s[2], s[3]));
    }
}

// ---------------- Pass 2: NMS ----------------
__global__ __launch_bounds__(256, 4) void nms_kernel(const float* __restrict__ in,
                                                     const float* __restrict__ partials,
                                                     float* __restrict__ out, int N) {
    // XCD-chunked swizzle: 8192 workgroups = 8 XCDs x 1024 (bijective, 8192%8==0).
    const int hwid = blockIdx.x + (blockIdx.y << 6);     // gridDim.x = 64 bands
    const int wg = ((hwid & 7) << 10) + (hwid >> 3);
    const int plane = wg >> 6;
    const int ty0 = (wg & 63) * TH;

    const float* pin = in + (size_t)plane * PLANE_ELEMS;

    __shared__ __align__(16) float sRow[LROWS * W];  // 28672 B -> 4-5 blocks/CU

    const int wid = threadIdx.x >> 6;   // wave 0..3
    const int lane = threadIdx.x & 63;
    const int c8 = lane << 3;           // 8 columns per lane; one wave = one full row

    // Plane max from the 32 partials (two cachelines, broadcast; issued early).
    float4 pm[8];
    #pragma unroll
    for (int j = 0; j < 8; ++j) pm[j] = *(const float4*)&partials[(plane << 5) + (j << 2)];

    // Phase A0: issue all row loads up front (independent dwordx4's).
    float4 va[4], vb[4];
    #pragma unroll
    for (int k = 0; k < 4; ++k) {
        const int r = wid + (k << 2);
        if (r < LROWS) {
            const int gy = ty0 + r - 3;
            if (gy >= 0 && gy < H) {
                const float4* row = (const float4*)(pin + (size_t)gy * W);
                va[k] = row[lane * 2];
                vb[k] = row[lane * 2 + 1];
            } else {
                va[k] = vb[k] = make_float4(NEG_INF, NEG_INF, NEG_INF, NEG_INF);
            }
        }
    }

    // Phase A1: horizontal 7-max entirely in registers (shuffle halo).
    #pragma unroll
    for (int k = 0; k < 4; ++k) {
        const int r = wid + (k << 2);
        if (r < LROWS) {   // wave-uniform guard: shuffles below are safe
            float4 v0 = va[k], v1 = vb[k];
            float l0 = __shfl_up(v1.y, 1, 64), l1 = __shfl_up(v1.z, 1, 64), l2 = __shfl_up(v1.w, 1, 64);
            float r0 = __shfl_down(v0.x, 1, 64), r1 = __shfl_down(v0.y, 1, 64), r2 = __shfl_down(v0.z, 1, 64);
            if (lane == 0) { l0 = NEG_INF; l1 = NEG_INF; l2 = NEG_INF; }
            if (lane == 63) { r0 = NEG_INF; r1 = NEG_INF; r2 = NEG_INF; }
            float a[14] = {l0, l1, l2, v0.x, v0.y, v0.z, v0.w, v1.x, v1.y, v1.z, v1.w, r0, r1, r2};
            // van Herk: rm[j] = max(a[j..j+6]), j=0..7; split at a[7]
            float A[7];
            A[6] = a[6];
            #pragma unroll
            for (int j = 5; j >= 0; --j) A[j] = fmaxf(a[j], A[j + 1]);
            float rm[8];
            rm[0] = A[0];
            float B = a[7];
            rm[1] = fmaxf(A[1], B);
            #pragma unroll
            for (int j = 2; j <= 6; ++j) { B = fmaxf(B, a[6 + j]); rm[j] = fmaxf(A[j], B); }
            B = fmaxf(B, a[13]);
            rm[7] = B;
            float4* dst = (float4*)&sRow[r * W + c8];
            dst[0] = make_float4(rm[0], rm[1], rm[2], rm[3]);
            dst[1] = make_float4(rm[4], rm[5], rm[6], rm[7]);
        }
    }

    // Phase B thread mapping.
    const int strip = threadIdx.x >> 7;       // 0/1 -> rows 0..3 / 4..7
    const int cg = threadIdx.x & 127;
    const int c = cg << 2;
    const int y0 = strip << 2;
    const int gy_base = ty0 + y0;

    // Prefetch center values BEFORE the barrier (L3/L2-hot after vmax pass).
    float4 ctr[4];
    #pragma unroll
    for (int i = 0; i < 4; ++i) {
        ctr[i] = *(const float4*)(pin + (size_t)(gy_base + i) * W + c);
    }

    // Reduce plane max (exact: fmax over disjoint chunks).
    float4 q = vmax4(vmax4(vmax4(pm[0], pm[1]), vmax4(pm[2], pm[3])),
                     vmax4(vmax4(pm[4], pm[5]), vmax4(pm[6], pm[7])));
    const float vmax = fmaxf(fmaxf(q.x, q.y), fmaxf(q.z, q.w));
    const float rel_thr = 0.05f * vmax;
    const float inv_vmax = 1.0f / vmax;

    __syncthreads();

    float* __restrict__ omask = out;
    float* __restrict__ oabs = out + (size_t)N;
    float* __restrict__ orel = out + 2 * (size_t)N;

    // Phase B: vertical 7-max (van Herk over 10 rows -> 4 outputs per thread).
    float4 Lr[7];
    #pragma unroll
    for (int k = 0; k < 7; ++k) Lr[k] = *(const float4*)&sRow[(y0 + k) * W + c];
    float4 Aq[4];
    {
        float4 suf = vmax4(Lr[4], vmax4(Lr[5], Lr[6]));
        Aq[3] = vmax4(Lr[3], suf);
        Aq[2] = vmax4(Lr[2], Aq[3]);
        Aq[1] = vmax4(Lr[1], Aq[2]);
        Aq[0] = vmax4(Lr[0], Aq[1]);
    }

    // Compute all 4 rows' score values into registers (no stores yet).
    float4 AV[4];
    float4 Bq;
    #pragma unroll
    for (int i = 0; i < 4; ++i) {
        float4 m;
        if (i == 0) {
            m = Aq[0];
        } else {
            float4 row = *(const float4*)&sRow[(y0 + 6 + i) * W + c];
            Bq = (i == 1) ? row : vmax4(Bq, row);
            m = vmax4(Aq[i], Bq);
        }
        const float4 cc = ctr[i];
        const bool p0 = (m.x == cc.x) & (cc.x > 0.2f) & (cc.x > rel_thr);
        const bool p1 = (m.y == cc.y) & (cc.y > 0.2f) & (cc.y > rel_thr);
        const bool p2 = (m.z == cc.z) & (cc.z > 0.2f) & (cc.z > rel_thr);
        const bool p3 = (m.w == cc.w) & (cc.w > 0.2f) & (cc.w > rel_thr);
        // note: p <=> value > 0 (peaks must exceed 0.2), so mask = (AV != 0)
        AV[i] = make_float4(p0 ? cc.x : 0.0f, p1 ? cc.y : 0.0f,
                            p2 ? cc.z : 0.0f, p3 ? cc.w : 0.0f);
    }

    const size_t ob = (size_t)plane * PLANE_ELEMS + (size_t)gy_base * W + c;

    // Stream-major NT store bursts: 4x mask, 4x abs, 4x rel.
    #pragma unroll
    for (int i = 0; i < 4; ++i) {
        nt_store4(omask + ob + (size_t)i * W,
                  AV[i].x != 0.0f ? 1.0f : 0.0f, AV[i].y != 0.0f ? 1.0f : 0.0f,
                  AV[i].z != 0.0f ? 1.0f : 0.0f, AV[i].w != 0.0f ? 1.0f : 0.0f);
    }
    #pragma unroll
    for (int i = 0; i < 4; ++i) {
        nt_store4(oabs + ob + (size_t)i * W, AV[i].x, AV[i].y, AV[i].z, AV[i].w);
    }
    #pragma unroll
    for (int i = 0; i < 4; ++i) {
        nt_store4(orel + ob + (size_t)i * W,
                  AV[i].x * inv_vmax, AV[i].y * inv_vmax,
                  AV[i].z * inv_vmax, AV[i].w * inv_vmax);
    }
}

extern "C" void kernel_launch(void* const* d_in, const int* in_sizes, int n_in,
                              void* d_out, int out_size, void* d_ws, size_t ws_size,
                              hipStream_t stream) {
    const float* in = (const float*)d_in[0];
    float* out = (float*)d_out;
    const int N = in_sizes[0];           // 33554432
    const int planes = N / PLANE_ELEMS;  // 128

    float* partials = (float*)d_ws;      // 128*32 floats = 16 KB

    vmax_kernel<<<dim3(VCHUNKS, planes), 256, 0, stream>>>(in, partials);
    nms_kernel<<<dim3(H / TH, planes), 256, 0, stream>>>(in, partials, out, N);
}